// Round 3
// baseline (214.854 us; speedup 1.0000x reference)
//
#include <hip/hip_runtime.h>

// Elementwise over B=8388608 rows of X:(B,4) f32 -> out:(B,2) f32.
// dur_us decomposition: timed region = 2 harness poison fills (~158us, fixed,
// 512MiB each @ ~6.7 TB/s) + this kernel. Kernel ideal: 201MB @ 6.6TB/s = ~30.5us.
// This version: grid-stride, 2048 blocks x 256 thr (32 waves/CU), 16 rows/thread
// in batches of 4 INDEPENDENT fully-coalesced float4 loads (streams offset by
// total thread count T) -> 4x memory-level parallelism per thread, every load
// and store instruction dense across the wave. hw trig (v_sin/v_cos): args
// <= ~21 rad, error ~4e-5 << passing absmax.

__device__ __forceinline__ float2 cgp_row(float4 x, float c0, float c1) {
    float n4 = x.x * x.y;
    float n5 = __sinf(n4 + c0);            // v_sin_f32 path
    float n6 = x.z * x.w;
    float n7 = fmaf(n5, n6, __sinf(x.z));
    float n8 = fmaf(__cosf(n7), c1, x.x);  // v_cos_f32 path
    return make_float2(n7, n8);
}

__global__ __launch_bounds__(256) void cgp_kernel(const float4* __restrict__ X,
                                                  const float* __restrict__ ephs,
                                                  float2* __restrict__ out,
                                                  int B) {
    const float c0 = ephs[0];   // wave-uniform -> s_load
    const float c1 = ephs[1];

    const int tid = blockIdx.x * blockDim.x + threadIdx.x;
    const int T   = gridDim.x * blockDim.x;   // 524288; B/T = 16 exactly

    int base = tid;
    // main batches: 4 independent coalesced streams in flight per thread
    for (; base + 3 * T < B; base += 4 * T) {
        float4 a = X[base];
        float4 b = X[base + T];
        float4 c = X[base + 2 * T];
        float4 d = X[base + 3 * T];

        float2 ra = cgp_row(a, c0, c1);
        float2 rb = cgp_row(b, c0, c1);
        float2 rc = cgp_row(c, c0, c1);
        float2 rd = cgp_row(d, c0, c1);

        out[base]         = ra;
        out[base + T]     = rb;
        out[base + 2 * T] = rc;
        out[base + 3 * T] = rd;
    }
    // tail (not taken for B=8388608, kept for generality)
    for (; base < B; base += T) {
        out[base] = cgp_row(X[base], c0, c1);
    }
}

extern "C" void kernel_launch(void* const* d_in, const int* in_sizes, int n_in,
                              void* d_out, int out_size, void* d_ws, size_t ws_size,
                              hipStream_t stream) {
    const float4* X  = (const float4*)d_in[0];
    const float* eph = (const float*)d_in[1];
    float2* out      = (float2*)d_out;
    int B = in_sizes[0] / 4;   // 8388608 rows

    const int block = 256;
    const int grid  = 2048;    // 524288 threads = 8192 waves = 32 waves/CU
    cgp_kernel<<<grid, block, 0, stream>>>(X, eph, out, B);
}

// Round 4
// 199.441 us; speedup vs baseline: 1.0773x; 1.0773x over previous
//
#include <hip/hip_runtime.h>

// Elementwise B=8388608 rows: X(B,4) f32 -> out(B,2) f32. 201 MB traffic,
// floor ~31us @ 6.3-6.7 TB/s. Timed region also contains 2 fixed 512MiB
// harness poison fills (~158us @ 6.7 TB/s measured on this box).
//
// Key change this round: FULL nontemporal (nt) access. The preceding 512MiB
// fill leaves L3 (256MiB) entirely dirty with poison; a caching kernel
// allocates ~192MiB of lines and forces that much dirty writeback onto its
// own critical path (~+25us). NT loads+stores allocate nothing: the dirty
// poison is overwritten in-cache by the NEXT iteration's fill and its
// writeback is skipped. Single-use streams lose nothing from cache bypass.
//
// Structure: the empirically-best round-0 shape (1 row/thread, no loop).
// hw trig (v_sin/v_cos): args <= ~21 rad, error ~4e-5 << passing absmax.

typedef float vfloat4 __attribute__((ext_vector_type(4)));
typedef float vfloat2 __attribute__((ext_vector_type(2)));

__global__ __launch_bounds__(256) void cgp_kernel(const vfloat4* __restrict__ X,
                                                  const float* __restrict__ ephs,
                                                  vfloat2* __restrict__ out,
                                                  int B) {
    int i = blockIdx.x * blockDim.x + threadIdx.x;
    if (i >= B) return;

    const float c0 = ephs[0];   // wave-uniform -> s_load
    const float c1 = ephs[1];

    vfloat4 x = __builtin_nontemporal_load(&X[i]);   // global_load_dwordx4 nt

    float n4 = x.x * x.y;
    float n5 = __sinf(n4 + c0);             // v_sin_f32
    float n6 = x.z * x.w;
    float n7 = fmaf(n5, n6, __sinf(x.z));
    float n8 = fmaf(__cosf(n7), c1, x.x);   // v_cos_f32

    vfloat2 r = {n7, n8};
    __builtin_nontemporal_store(r, &out[i]);         // global_store_dwordx2 nt
}

extern "C" void kernel_launch(void* const* d_in, const int* in_sizes, int n_in,
                              void* d_out, int out_size, void* d_ws, size_t ws_size,
                              hipStream_t stream) {
    const vfloat4* X = (const vfloat4*)d_in[0];
    const float* eph = (const float*)d_in[1];
    vfloat2* out     = (vfloat2*)d_out;
    int B = in_sizes[0] / 4;   // 8388608 rows

    const int block = 256;
    const int grid  = (B + block - 1) / block;   // 32768 blocks
    cgp_kernel<<<grid, block, 0, stream>>>(X, eph, out, B);
}